// Round 2
// baseline (135.414 us; speedup 1.0000x reference)
//
#include <hip/hip_runtime.h>
#include <hip/hip_cooperative_groups.h>

namespace cg = cooperative_groups;

// ContinuousCRF: mean-field CRF on a 96x96 grid, 3 classes, 5 iterations.
// The dense [N,N] pairwise kernel is a translation-invariant 11x11
// circular-mask convolution (radius 5, weight exp(-dist), no center tap).
// Each iteration: q = softmax(unary + Comp @ conv(q)).
// Round 2: single cooperative launch, grid.sync() between iterations
// (replaces 4 kernel-launch boundaries; 36 blocks << 256 CUs so
// co-residency is guaranteed by the cooperative launch).

constexpr int HH = 96, WW = 96, NN = HH * WW;
constexpr int TILE = 16, HALO = 5, EXT = TILE + 2 * HALO; // 26

__global__ __launch_bounds__(TILE * TILE) void crf_fused(
    const float* __restrict__ unary,   // [3][9216] planes
    const float* __restrict__ comp,    // [3][3]
    float4* __restrict__ zA,           // ping-pong logits in ws
    float4* __restrict__ zB,
    float* __restrict__ qout)          // [3][9216] final q
{
    cg::grid_group grid = cg::this_grid();

    __shared__ float4 qs[EXT][EXT];    // softmax'd q over tile+halo
    __shared__ float wtab[121];        // 11x11 conv weights

    const int tx = threadIdx.x, ty = threadIdx.y;
    const int tid = ty * TILE + tx;

    // Conv weight table (once; exact math).
    if (tid < 121) {
        int dy = tid / 11 - 5, dx = tid % 11 - 5;
        int d2 = dy * dy + dx * dx;
        wtab[tid] = (d2 > 0 && d2 <= 25) ? expf(-sqrtf((float)d2)) : 0.0f;
    }

    // Compatibility matrix in registers (3x3 row-major).
    const float c00 = comp[0], c01 = comp[1], c02 = comp[2];
    const float c10 = comp[3], c11 = comp[4], c12 = comp[5];
    const float c20 = comp[6], c21 = comp[7], c22 = comp[8];

    const int bx0 = blockIdx.x * TILE, by0 = blockIdx.y * TILE;
    const int n_out = (by0 + ty) * WW + (bx0 + tx);
    const float u0 = unary[n_out];
    const float u1 = unary[NN + n_out];
    const float u2 = unary[2 * NN + n_out];

    constexpr int XLO[11] = {5, 2, 1, 1, 1, 0, 1, 1, 1, 2, 5};
    constexpr int XHI[11] = {5, 8, 9, 9, 9, 10, 9, 9, 9, 8, 5};

    for (int it = 0; it < 5; ++it) {
        const float4* zin = (it & 1) ? zB : zA;   // valid for it>=1

        // Stage softmax(z) for the 26x26 halo tile into LDS.
        // Out-of-image -> q=0 (zero connectivity outside the grid).
        for (int i = tid; i < EXT * EXT; i += TILE * TILE) {
            int hy = i / EXT, hx = i - hy * EXT;
            int gy = by0 + hy - HALO, gx = bx0 + hx - HALO;
            float4 q = make_float4(0.f, 0.f, 0.f, 0.f);
            if (gy >= 0 && gy < HH && gx >= 0 && gx < WW) {
                int n = gy * WW + gx;
                float z0, z1, z2;
                if (it == 0) {
                    z0 = unary[n];
                    z1 = unary[NN + n];
                    z2 = unary[2 * NN + n];
                } else {
                    float4 z = zin[n];
                    z0 = z.x; z1 = z.y; z2 = z.z;
                }
                float mx = fmaxf(z0, fmaxf(z1, z2));
                float e0 = expf(z0 - mx), e1 = expf(z1 - mx), e2 = expf(z2 - mx);
                float inv = 1.0f / (e0 + e1 + e2);
                q = make_float4(e0 * inv, e1 * inv, e2 * inv, 0.f);
            }
            qs[hy][hx] = q;
        }
        __syncthreads();

        // 11x11 conv, static per-row dx bounds (circle mask) -> 81 taps.
        float m0 = 0.f, m1 = 0.f, m2 = 0.f;
#pragma unroll
        for (int dyi = 0; dyi < 11; ++dyi) {
#pragma unroll
            for (int dxi = XLO[dyi]; dxi <= XHI[dyi]; ++dxi) {
                float w = wtab[dyi * 11 + dxi];   // wave-uniform broadcast
                float4 q = qs[ty + dyi][tx + dxi];
                m0 = fmaf(w, q.x, m0);
                m1 = fmaf(w, q.y, m1);
                m2 = fmaf(w, q.z, m2);
            }
        }

        float t0 = c00 * m0 + c01 * m1 + c02 * m2;
        float t1 = c10 * m0 + c11 * m1 + c12 * m2;
        float t2 = c20 * m0 + c21 * m1 + c22 * m2;

        float z0 = u0 + t0, z1 = u1 + t1, z2 = u2 + t2;

        if (it == 4) {
            float mx = fmaxf(z0, fmaxf(z1, z2));
            float e0 = expf(z0 - mx), e1 = expf(z1 - mx), e2 = expf(z2 - mx);
            float inv = 1.0f / (e0 + e1 + e2);
            qout[n_out] = e0 * inv;
            qout[NN + n_out] = e1 * inv;
            qout[2 * NN + n_out] = e2 * inv;
        } else {
            float4* zout = (it & 1) ? zA : zB;
            zout[n_out] = make_float4(z0, z1, z2, 0.f);
            __threadfence();   // make z visible device-wide before the barrier
            grid.sync();       // also serves as the block barrier before LDS reuse
        }
    }
}

extern "C" void kernel_launch(void* const* d_in, const int* in_sizes, int n_in,
                              void* d_out, int out_size, void* d_ws, size_t ws_size,
                              hipStream_t stream) {
    const float* unary = (const float*)d_in[0];
    const float* comp = (const float*)d_in[1];
    float* out = (float*)d_out;

    // Ping-pong logit buffers in workspace: 2 * 9216 * 16 B = 288 KiB.
    float4* zA = (float4*)d_ws;
    float4* zB = zA + NN;

    dim3 grid(WW / TILE, HH / TILE);  // 6x6 = 36 blocks
    dim3 block(TILE, TILE);           // 256 threads

    void* args[] = {(void*)&unary, (void*)&comp, (void*)&zA, (void*)&zB, (void*)&out};
    hipLaunchCooperativeKernel((const void*)crf_fused, grid, block, args, 0, stream);
}

// Round 3
// 92.465 us; speedup vs baseline: 1.4645x; 1.4645x over previous
//
#include <hip/hip_runtime.h>

// ContinuousCRF: mean-field CRF on a 96x96 grid, 3 classes, 5 iterations.
// The dense [N,N] pairwise kernel is a translation-invariant 11x11
// circular-mask convolution (radius 5, weight exp(-dist), no center tap).
// Each iteration: q = softmax(unary + Comp @ conv(q)).
//
// Round 3: NO grid sync (R2's coop grid.sync+threadfence cost ~12us each).
// Fuse iterations inside a block via redundant halo compute: a block owning
// a T x T output tile after K iterations stages (T+10K)^2 of q and shrinks
// the computed region by 5/side each iteration, with only __syncthreads().
// Split 5 iters = K=3 launch + K=2 launch (LDS-BW optimum at T=8).

constexpr int HH = 96, WW = 96, NN = HH * WW;
constexpr int T = 8;

template <int K, bool FIRST, bool LAST>
__global__ __launch_bounds__(256) void crf_multi(
    const float* __restrict__ unary,   // [3][9216] planes
    const float* __restrict__ comp,    // [3][3]
    const float4* __restrict__ zin,    // logits in (if !FIRST)
    float4* __restrict__ zout,         // logits out (if !LAST)
    float* __restrict__ qout)          // [3][9216] final q (if LAST)
{
    constexpr int EXT = T + 10 * K;
    __shared__ float4 qa[EXT][EXT + 1];   // +1 float4 pad vs bank conflicts
    __shared__ float4 qb[EXT][EXT + 1];
    __shared__ float wtab[121];

    const int tid = threadIdx.x;

    // 11x11 conv weight table (exact math, once per block).
    if (tid < 121) {
        int dy = tid / 11 - 5, dx = tid % 11 - 5;
        int d2 = dy * dy + dx * dx;
        wtab[tid] = (d2 > 0 && d2 <= 25) ? expf(-sqrtf((float)d2)) : 0.0f;
    }

    // Compatibility matrix (3x3 row-major), wave-uniform scalar loads.
    const float c00 = comp[0], c01 = comp[1], c02 = comp[2];
    const float c10 = comp[3], c11 = comp[4], c12 = comp[5];
    const float c20 = comp[6], c21 = comp[7], c22 = comp[8];

    // Global coords of ext-region origin (may be negative / off-image).
    const int bx0 = blockIdx.x * T - 5 * K;
    const int by0 = blockIdx.y * T - 5 * K;

    // Stage q^0 = softmax(z) over the EXT x EXT region into qa.
    // Off-image -> q = 0 (zero connectivity outside the grid).
    for (int i = tid; i < EXT * EXT; i += 256) {
        int hy = i / EXT, hx = i - hy * EXT;
        int gy = by0 + hy, gx = bx0 + hx;
        float4 q = make_float4(0.f, 0.f, 0.f, 0.f);
        if (gy >= 0 && gy < HH && gx >= 0 && gx < WW) {
            int n = gy * WW + gx;
            float z0, z1, z2;
            if (FIRST) {
                z0 = unary[n]; z1 = unary[NN + n]; z2 = unary[2 * NN + n];
            } else {
                float4 z = zin[n];
                z0 = z.x; z1 = z.y; z2 = z.z;
            }
            float mx = fmaxf(z0, fmaxf(z1, z2));
            float e0 = expf(z0 - mx), e1 = expf(z1 - mx), e2 = expf(z2 - mx);
            float inv = 1.0f / (e0 + e1 + e2);
            q = make_float4(e0 * inv, e1 * inv, e2 * inv, 0.f);
        }
        qa[hy][hx] = q;
    }
    __syncthreads();   // also covers wtab

    constexpr int XLO[11] = {5, 2, 1, 1, 1, 0, 1, 1, 1, 2, 5};
    constexpr int XHI[11] = {5, 8, 9, 9, 9, 10, 9, 9, 9, 8, 5};

#pragma unroll
    for (int k = 1; k <= K; ++k) {
        const int R = T + 10 * (K - k);   // computed region this iter
        const int o = 5 * k;              // its offset in ext coords
        const bool rd_a = (k & 1);        // k odd: read qa, write qb

        for (int i = tid; i < R * R; i += 256) {
            int py = i / R, px = i - py * R;
            int ey = o + py, ex = o + px;
            int gy = by0 + ey, gx = bx0 + ex;
            float4 qnew = make_float4(0.f, 0.f, 0.f, 0.f);
            if (gy >= 0 && gy < HH && gx >= 0 && gx < WW) {
                float m0 = 0.f, m1 = 0.f, m2 = 0.f;
#pragma unroll
                for (int dyi = 0; dyi < 11; ++dyi) {
#pragma unroll
                    for (int dxi = XLO[dyi]; dxi <= XHI[dyi]; ++dxi) {
                        float w = wtab[dyi * 11 + dxi];  // uniform broadcast
                        float4 q = rd_a ? qa[ey - 5 + dyi][ex - 5 + dxi]
                                        : qb[ey - 5 + dyi][ex - 5 + dxi];
                        m0 = fmaf(w, q.x, m0);
                        m1 = fmaf(w, q.y, m1);
                        m2 = fmaf(w, q.z, m2);
                    }
                }
                float t0 = c00 * m0 + c01 * m1 + c02 * m2;
                float t1 = c10 * m0 + c11 * m1 + c12 * m2;
                float t2 = c20 * m0 + c21 * m1 + c22 * m2;

                int n = gy * WW + gx;
                float z0 = unary[n] + t0;
                float z1 = unary[NN + n] + t1;
                float z2 = unary[2 * NN + n] + t2;

                if (k == K) {
                    // Region == the block's own T x T tile (all in-image).
                    if (LAST) {
                        float mx = fmaxf(z0, fmaxf(z1, z2));
                        float e0 = expf(z0 - mx), e1 = expf(z1 - mx),
                              e2 = expf(z2 - mx);
                        float inv = 1.0f / (e0 + e1 + e2);
                        qout[n] = e0 * inv;
                        qout[NN + n] = e1 * inv;
                        qout[2 * NN + n] = e2 * inv;
                    } else {
                        zout[n] = make_float4(z0, z1, z2, 0.f);
                    }
                } else {
                    float mx = fmaxf(z0, fmaxf(z1, z2));
                    float e0 = expf(z0 - mx), e1 = expf(z1 - mx),
                          e2 = expf(z2 - mx);
                    float inv = 1.0f / (e0 + e1 + e2);
                    qnew = make_float4(e0 * inv, e1 * inv, e2 * inv, 0.f);
                }
            }
            if (k < K) {
                if (rd_a) qb[ey][ex] = qnew; else qa[ey][ex] = qnew;
            }
        }
        if (k < K) __syncthreads();
        // Next iter reads only ext coords [o, o+R) — exactly what was written.
    }
}

extern "C" void kernel_launch(void* const* d_in, const int* in_sizes, int n_in,
                              void* d_out, int out_size, void* d_ws, size_t ws_size,
                              hipStream_t stream) {
    const float* unary = (const float*)d_in[0];
    const float* comp = (const float*)d_in[1];
    float* out = (float*)d_out;

    float4* zA = (float4*)d_ws;   // 9216 * 16 B = 144 KiB

    dim3 grid(WW / T, HH / T);    // 12x12 = 144 blocks
    dim3 block(256);

    // Iters 1-3 (halo 15), then iters 4-5 (halo 10).
    crf_multi<3, true,  false><<<grid, block, 0, stream>>>(unary, comp, nullptr, zA, nullptr);
    crf_multi<2, false, true ><<<grid, block, 0, stream>>>(unary, comp, zA, nullptr, out);
}

// Round 4
// 79.828 us; speedup vs baseline: 1.6963x; 1.1583x over previous
//
#include <hip/hip_runtime.h>

// ContinuousCRF: mean-field CRF on a 96x96 grid, 3 classes, 5 iterations.
// The dense [N,N] pairwise kernel is a translation-invariant 11x11
// circular-mask convolution (radius 5, weight exp(-dist), no center tap).
// Each iteration: q = softmax(unary + Comp @ conv(q)).
//
// Round 4: fixed-overhead model says graph nodes are ~free (R1 5-node and
// R2 1-node share the same ~70us fixed cost: 39us harness ws-poison fill +
// ~31us restore/out-poison/sync). So: 5 single-iteration launches, zero
// redundant compute, max CU coverage: T=8 tiles -> 144 blocks of 64 threads
// (R1 used only 36 CUs). Hand q (not logits) between iterations so halo
// staging is a pure float4 copy (no softmax recompute in staging).

constexpr int HH = 96, WW = 96, NN = HH * WW;
constexpr int T = 8, HALO = 5, EXT = T + 2 * HALO; // 18

template <bool FIRST, bool LAST>
__global__ __launch_bounds__(64) void crf_iter(
    const float* __restrict__ unary,   // [3][9216] planes
    const float* __restrict__ comp,    // [3][3]
    const float4* __restrict__ qin,    // q from previous iter (if !FIRST)
    float4* __restrict__ qnext,        // q out as float4 (if !LAST)
    float* __restrict__ qout)          // [3][9216] final q planes (if LAST)
{
    __shared__ float4 qs[EXT][EXT + 1];  // q over tile+halo (+1 float4 pad)
    __shared__ float wtab[121];          // 11x11 conv weights

    const int tid = threadIdx.x;

    // Conv weight table (exact math; 2 passes of 64 threads).
    for (int i = tid; i < 121; i += 64) {
        int dy = i / 11 - 5, dx = i % 11 - 5;
        int d2 = dy * dy + dx * dx;
        wtab[i] = (d2 > 0 && d2 <= 25) ? expf(-sqrtf((float)d2)) : 0.0f;
    }

    // Compatibility matrix (3x3 row-major), wave-uniform scalar loads.
    const float c00 = comp[0], c01 = comp[1], c02 = comp[2];
    const float c10 = comp[3], c11 = comp[4], c12 = comp[5];
    const float c20 = comp[6], c21 = comp[7], c22 = comp[8];

    const int bx0 = blockIdx.x * T - HALO;
    const int by0 = blockIdx.y * T - HALO;

    // Stage q over the 18x18 halo region. FIRST: q0 = softmax(unary);
    // otherwise a straight float4 copy. Off-image -> q = 0.
    for (int i = tid; i < EXT * EXT; i += 64) {
        int hy = i / EXT, hx = i - hy * EXT;
        int gy = by0 + hy, gx = bx0 + hx;
        float4 q = make_float4(0.f, 0.f, 0.f, 0.f);
        if (gy >= 0 && gy < HH && gx >= 0 && gx < WW) {
            int n = gy * WW + gx;
            if (FIRST) {
                float z0 = unary[n], z1 = unary[NN + n], z2 = unary[2 * NN + n];
                float mx = fmaxf(z0, fmaxf(z1, z2));
                float e0 = expf(z0 - mx), e1 = expf(z1 - mx), e2 = expf(z2 - mx);
                float inv = 1.0f / (e0 + e1 + e2);
                q = make_float4(e0 * inv, e1 * inv, e2 * inv, 0.f);
            } else {
                q = qin[n];
            }
        }
        qs[hy][hx] = q;
    }
    __syncthreads();   // single-wave block: near-free barrier

    // 11x11 conv, static per-row dx bounds (circle mask) -> 81 taps.
    const int ty = tid >> 3, tx = tid & 7;   // 8x8 tile, 1 px/thread
    float m0 = 0.f, m1 = 0.f, m2 = 0.f;
    constexpr int XLO[11] = {5, 2, 1, 1, 1, 0, 1, 1, 1, 2, 5};
    constexpr int XHI[11] = {5, 8, 9, 9, 9, 10, 9, 9, 9, 8, 5};
#pragma unroll
    for (int dyi = 0; dyi < 11; ++dyi) {
#pragma unroll
        for (int dxi = XLO[dyi]; dxi <= XHI[dyi]; ++dxi) {
            float w = wtab[dyi * 11 + dxi];   // wave-uniform broadcast
            float4 q = qs[ty + dyi][tx + dxi];
            m0 = fmaf(w, q.x, m0);
            m1 = fmaf(w, q.y, m1);
            m2 = fmaf(w, q.z, m2);
        }
    }

    float t0 = c00 * m0 + c01 * m1 + c02 * m2;
    float t1 = c10 * m0 + c11 * m1 + c12 * m2;
    float t2 = c20 * m0 + c21 * m1 + c22 * m2;

    const int n = (blockIdx.y * T + ty) * WW + (blockIdx.x * T + tx);
    float z0 = unary[n] + t0;
    float z1 = unary[NN + n] + t1;
    float z2 = unary[2 * NN + n] + t2;

    float mx = fmaxf(z0, fmaxf(z1, z2));
    float e0 = expf(z0 - mx), e1 = expf(z1 - mx), e2 = expf(z2 - mx);
    float inv = 1.0f / (e0 + e1 + e2);

    if (LAST) {
        qout[n] = e0 * inv;
        qout[NN + n] = e1 * inv;
        qout[2 * NN + n] = e2 * inv;
    } else {
        qnext[n] = make_float4(e0 * inv, e1 * inv, e2 * inv, 0.f);
    }
}

extern "C" void kernel_launch(void* const* d_in, const int* in_sizes, int n_in,
                              void* d_out, int out_size, void* d_ws, size_t ws_size,
                              hipStream_t stream) {
    const float* unary = (const float*)d_in[0];
    const float* comp = (const float*)d_in[1];
    float* out = (float*)d_out;

    // Ping-pong q buffers in workspace: 2 * 9216 * 16 B = 288 KiB.
    float4* qA = (float4*)d_ws;
    float4* qB = qA + NN;

    dim3 grid(WW / T, HH / T);    // 12x12 = 144 blocks (1 wave each)
    dim3 block(64);

    crf_iter<true,  false><<<grid, block, 0, stream>>>(unary, comp, nullptr, qA, nullptr);
    crf_iter<false, false><<<grid, block, 0, stream>>>(unary, comp, qA, qB, nullptr);
    crf_iter<false, false><<<grid, block, 0, stream>>>(unary, comp, qB, qA, nullptr);
    crf_iter<false, false><<<grid, block, 0, stream>>>(unary, comp, qA, qB, nullptr);
    crf_iter<false, true ><<<grid, block, 0, stream>>>(unary, comp, qB, nullptr, out);
}